// Round 3
// baseline (9.558 us; speedup 1.0000x reference)
//
#include <hip/hip_runtime.h>
#include <math.h>

// Fused Net_6maxFull, round 3: gates+nonlinearity merged per thread (no gate
// LDS round-trip), uniform x via s_loads, 3 barriers total, 384 threads.

__device__ __forceinline__ float fsig(float v) {
    return __fdividef(1.0f, 1.0f + __expf(-v));
}
__device__ __forceinline__ float ftanh(float v) {
    return 1.0f - __fdividef(2.0f, 1.0f + __expf(2.0f * v));
}

__global__ __launch_bounds__(384) void net6max_kernel(
    const float* __restrict__ x,        // [37]
    const float* __restrict__ gen_Wih,  // [10][40][12]
    const float* __restrict__ gen_Whh,  // [10][40][10]
    const float* __restrict__ gen_bih,  // [10][40]
    const float* __restrict__ gen_bhh,  // [10][40]
    const float* __restrict__ gen_h0,   // [10][10]
    const float* __restrict__ gen_c0,   // [10][10]
    const float* __restrict__ game_Wih, // [5][10][20][4]
    const float* __restrict__ game_Whh, // [5][10][20][5]
    const float* __restrict__ game_bih, // [5][10][20]
    const float* __restrict__ game_bhh, // [5][10][20]
    const float* __restrict__ game_h0,  // [5][10][5]
    const float* __restrict__ game_c0,  // [5][10][5]
    const float* __restrict__ W1,       // [50][200]
    const float* __restrict__ b1,       // [50]
    const float* __restrict__ W2,       // [10][50]
    const float* __restrict__ b2,       // [10]
    const float* __restrict__ W3,       // [1][10]
    const float* __restrict__ b3,       // [1]
    float* __restrict__ out)            // [1]
{
    __shared__ __align__(16) float s_hgame[5][10][5];
    __shared__ __align__(16) float s_test[200];
    __shared__ __align__(16) float s_h1[52];

    const int tid = threadIdx.x;

    // ============ Phase 1: full LSTM cells, gates in-register ============
    if (tid < 100) {
        // gen cell (k, j): gates rows {j, 10+j, 20+j, 30+j}
        int k = tid / 10, j = tid % 10;
        const float*  Wk  = gen_Wih + (size_t)k * 480;   // [40][12]
        const float*  Uk  = gen_Whh + (size_t)k * 400;   // [40][10]
        const float*  bi  = gen_bih + k * 40;
        const float*  bh  = gen_bhh + k * 40;
        const float2* h02 = (const float2*)(gen_h0 + k * 10);
        float2 h0a = h02[0], h0b = h02[1], h0c = h02[2], h0d = h02[3], h0e = h02[4];
        float4 xa = *(const float4*)&x[0];   // uniform, 16B aligned
        float4 xb = *(const float4*)&x[4];
        float4 xc = *(const float4*)&x[8];
        float g4[4];
        #pragma unroll
        for (int gq = 0; gq < 4; ++gq) {
            int r = gq * 10 + j;
            const float4* w4 = (const float4*)(Wk + r * 12);  // r*12 % 4 == 0
            const float2* u2 = (const float2*)(Uk + r * 10);
            float4 p = w4[0] * xa + w4[1] * xb + w4[2] * xc;
            float2 q = u2[0] * h0a + u2[1] * h0b + u2[2] * h0c
                     + u2[3] * h0d + u2[4] * h0e;
            g4[gq] = bi[r] + bh[r] + p.x + p.y + p.z + p.w + q.x + q.y;
        }
        float c = fsig(g4[1]) * gen_c0[tid] + fsig(g4[0]) * ftanh(g4[2]);
        s_test[tid] = fsig(g4[3]) * ftanh(c);
    } else if (tid >= 128 && tid < 378) {
        // game cell (o, k, j): gates rows {j, 5+j, 10+j, 15+j}
        int u = tid - 128;
        int o = u / 50;
        int rem = u % 50;
        int k = rem / 5, j = rem % 5;
        int ok = o * 10 + k;
        const float* Wk = game_Wih + (size_t)ok * 80;    // [20][4]
        const float* Uk = game_Whh + (size_t)ok * 100;   // [20][5]
        const float* bi = game_bih + ok * 20;
        const float* bh = game_bhh + ok * 20;
        const float* h0 = game_h0 + ok * 5;
        float h00 = h0[0], h01 = h0[1], h02_ = h0[2], h03 = h0[3], h04 = h0[4];
        const float* fx = x + 13 + 5 * o;                // feats row o
        float f0 = fx[0], f1 = fx[1], f2 = fx[2], f3 = fx[3];
        float g4[4];
        #pragma unroll
        for (int gq = 0; gq < 4; ++gq) {
            int r = gq * 5 + j;
            float4 w = *(const float4*)(Wk + r * 4);     // r*4 % 4 == 0
            const float* uu = Uk + r * 5;
            float acc = bi[r] + bh[r]
                      + w.x * f0 + w.y * f1 + w.z * f2 + w.w * f3;
            acc += uu[0]*h00 + uu[1]*h01 + uu[2]*h02_ + uu[3]*h03 + uu[4]*h04;
            g4[gq] = acc;
        }
        float c = fsig(g4[1]) * game_c0[ok * 5 + j] + fsig(g4[0]) * ftanh(g4[2]);
        s_hgame[o][k][j] = fsig(g4[3]) * ftanh(c);
    }
    __syncthreads();

    // ============ Phase 2: masked average -> test[100..199] ============
    if (tid < 100) {
        float msum = 0.0f, acc = 0.0f;
        #pragma unroll
        for (int o = 0; o < 5; ++o) {
            float m = (x[12 + 5 * o] == 1.0f) ? 1.0f : 0.0f;  // uniform s_load
            msum += m;
            float v = (tid < 50) ? s_hgame[o][tid / 5][tid % 5]
                                 : s_hgame[o][9][tid % 5];
            acc += m * v;
        }
        s_test[100 + tid] = __fdividef(acc, msum);
    }
    __syncthreads();

    // ============ Phase 3: MLP layer 1 (50x200), 4 threads/row ============
    if (tid < 200) {
        int r = tid >> 2, q = tid & 3;
        const float4* w4 = (const float4*)(W1 + (size_t)r * 200);
        const float4* t4 = (const float4*)s_test;
        float4 acc4 = make_float4(0.f, 0.f, 0.f, 0.f);
        #pragma unroll
        for (int m = 0; m < 12; ++m) {
            int c4 = q + 4 * m;
            acc4 += w4[c4] * t4[c4];
        }
        if (q < 2) {
            int c4 = 48 + q;
            acc4 += w4[c4] * t4[c4];
        }
        float acc = acc4.x + acc4.y + acc4.z + acc4.w;
        acc += __shfl_xor(acc, 1);
        acc += __shfl_xor(acc, 2);
        if (q == 0) s_h1[r] = ftanh(acc + b1[r]);
    }
    __syncthreads();

    // ===== Phase 4: layers 2+3 fused in wave 0 (no barrier between) =====
    if (tid < 32) {
        float acc = 0.f;
        if (tid < 20) {
            int r = tid >> 1, q = tid & 1;
            const float2* w2 = (const float2*)(W2 + (size_t)r * 50);
            const float2* h1v = (const float2*)s_h1;
            float2 acc2 = make_float2(0.f, 0.f);
            #pragma unroll
            for (int m = 0; m < 12; ++m) {
                int c = q + 2 * m;
                acc2 += w2[c] * h1v[c];
            }
            if (q == 0) acc2 += w2[24] * h1v[24];
            float a = acc2.x + acc2.y;
            a += __shfl_xor(a, 1);                 // pair reduce (q=0,1)
            acc = (q == 0) ? ftanh(a + b2[r]) * W3[r] : 0.f;
        }
        // reduce h2[r]*W3[r] over lanes 0..31 (non-contributors are 0)
        acc += __shfl_xor(acc, 2);
        acc += __shfl_xor(acc, 4);
        acc += __shfl_xor(acc, 8);
        acc += __shfl_xor(acc, 16);
        acc += __shfl_xor(acc, 1);
        if (tid == 0) out[0] = ftanh(acc + b3[0]);
    }
}

extern "C" void kernel_launch(void* const* d_in, const int* in_sizes, int n_in,
                              void* d_out, int out_size, void* d_ws, size_t ws_size,
                              hipStream_t stream) {
    (void)in_sizes; (void)n_in; (void)out_size; (void)d_ws; (void)ws_size;
    const float* x        = (const float*)d_in[0];
    const float* gen_Wih  = (const float*)d_in[1];
    const float* gen_Whh  = (const float*)d_in[2];
    const float* gen_bih  = (const float*)d_in[3];
    const float* gen_bhh  = (const float*)d_in[4];
    const float* gen_h0   = (const float*)d_in[5];
    const float* gen_c0   = (const float*)d_in[6];
    const float* game_Wih = (const float*)d_in[7];
    const float* game_Whh = (const float*)d_in[8];
    const float* game_bih = (const float*)d_in[9];
    const float* game_bhh = (const float*)d_in[10];
    const float* game_h0  = (const float*)d_in[11];
    const float* game_c0  = (const float*)d_in[12];
    const float* W1       = (const float*)d_in[13];
    const float* b1       = (const float*)d_in[14];
    const float* W2       = (const float*)d_in[15];
    const float* b2       = (const float*)d_in[16];
    const float* W3       = (const float*)d_in[17];
    const float* b3       = (const float*)d_in[18];
    float* out = (float*)d_out;

    net6max_kernel<<<1, 384, 0, stream>>>(
        x, gen_Wih, gen_Whh, gen_bih, gen_bhh, gen_h0, gen_c0,
        game_Wih, game_Whh, game_bih, game_bhh, game_h0, game_c0,
        W1, b1, W2, b2, W3, b3, out);
}